// Round 6
// baseline (1406.469 us; speedup 1.0000x reference)
//
#include <hip/hip_runtime.h>
#include <math.h>

#define TT 512
#define BB 4096
#define IN_DIM 12
#define HH 32
#define LL 10
#define CC 4
#define NTH 768          // 12 waves: 8 full layers + 2 split layers (L8, L9)

typedef _Float16 half8 __attribute__((ext_vector_type(8)));
typedef _Float16 half4 __attribute__((ext_vector_type(4)));
typedef float f32x4 __attribute__((ext_vector_type(4)));
typedef float f32x2 __attribute__((ext_vector_type(2)));

#define LOG2E 1.44269504088896340736f

// f16-unit offsets in the LDS arena (total 53248 f16 = 104 KB static):
//  H_HI: per-layer h hi panels, 8 slots (mod-8 of t) — cross-wave handoff
//  H_LO: per-layer h lo panels, 2 slots — own-layer recurrence
//  X_HI: wave-0 x panels, 4 slots — wave-internal
#define H_HI 0
#define H_LO (LL * 8 * 512)             // 40960
#define X_HI (H_LO + LL * 2 * 512)      // 51200
#define LDS16_TOT (X_HI + 4 * 512)      // 53248

#define MFMA_(A, B, C) C = __builtin_amdgcn_mfma_f32_16x16x32_f16(A, B, C, 0, 0, 0)

// Fused 10-layer GRU, temporal pipeline, MFMA cells, self-timed flags.
//
// Session ledger:
//  R1: batched-rcp ~neutral -> trans are cheap; VALUBusy includes MFMA.
//  R2: 4-wave multi-cell FAILED (VGPR 370 >> 196 -> serialized). TLP is
//      load-bearing.
//  R4/R5: pk-epilogue + 8-slot H_HI = -51us (952->901); s_setprio = -110us
//      HARM (starves co-resident epilogue VALU on the recurrence path).
//      BANNED on this structure.
//  R6 (this round): SIMD balance. 10 waves place {3,3,2,2} (w%4) ->
//      critical SIMDs 62% busy, light ones 41%. Split layers 8,9 into
//      M-halves (jt): 12 waves, one half-wave per SIMD -> {full,full,half}
//      = balanced 2194 cyc/substep issue per SIMD (-17% on critical).
//      Halves exchange h-halves via per-substep sibling flags.
//      Per-element arithmetic identical -> absmax must stay 0.0078125.
__global__ __launch_bounds__(NTH, 2)
void gru_fused_mfma(const float* __restrict__ x,      // [T][B][12]
                    const float* __restrict__ Wih0,   // [96][12]
                    const float* __restrict__ Whh0,   // [96][32]
                    const float* __restrict__ bih0,   // [96]
                    const float* __restrict__ bhh0,   // [96]
                    const float* __restrict__ Wih,    // [9][96][32]
                    const float* __restrict__ Whh,    // [9][96][32]
                    const float* __restrict__ bih,    // [9][96]
                    const float* __restrict__ bhh,    // [9][96]
                    const int*   __restrict__ lengths,
                    float*       __restrict__ last)   // [B][32]
{
    __shared__ __align__(16) _Float16 lds16[LDS16_TOT];
    __shared__ int flagS[12];    // producer progress, indexed by wave id
    __shared__ int rflagS[12];   // consumer progress, indexed by wave id
    __shared__ int sibF[4];      // sibling substep progress: waves 8..11

    const int tid  = threadIdx.x;
    const int w    = tid >> 6;      // wave id
    const int lane = tid & 63;
    const int bi16 = lane & 15;     // batch col within group
    const int quad = lane >> 4;
    const int bg   = blockIdx.x;    // batch group (16 elems)

    // wave roles: w 0..7 full (layer w); w 8,9 = L8 halves jt=w-8;
    // w 10,11 = L9 halves jt=w-10. Round-robin w%4 -> one half per SIMD.
    const int  layer  = (w < 8) ? w : ((w < 10) ? 8 : 9);
    const bool isHalf = (w >= 8);
    const int  myjt   = (w < 8) ? 0 : ((w < 10) ? (w - 8) : (w - 10));

    // ---- zero the arena (h0 = 0, zero-padding) + init flags ----
    {
        float4 z4 = make_float4(0.f, 0.f, 0.f, 0.f);
        float4* p = (float4*)lds16;
        for (int i = tid; i < LDS16_TOT / 8; i += NTH) p[i] = z4;
    }
    if (lane == 0) { flagS[w] = -1; rflagS[w] = -1; }
    if (tid < 4) sibF[tid] = -1;
    __syncthreads();

    // ---- per-layer weight pointers ----
    const float *Wi, *Wh, *bivec, *bhvec;
    int wistride;
    if (layer == 0) { Wi = Wih0; Wh = Whh0; bivec = bih0; bhvec = bhh0; wistride = IN_DIM; }
    else {
        Wi = Wih + (size_t)(layer - 1) * 96 * HH;
        Wh = Whh + (size_t)(layer - 1) * 96 * HH;
        bivec = bih + (size_t)(layer - 1) * 96;
        bhvec = bhh + (size_t)(layer - 1) * 96;
        wistride = HH;
    }

    // ---- stationary A-fragments (pre-scaled) ----
    const int frow[12] = {0, 0, 16, 16, 32, 32, 48, 48, 64, 80, 64, 80};
    const int fchk[12] = {0, 1, 0, 1, 0, 1, 0, 1, 0, 0, 1, 1};
    half8 Whi[12], Wlo[6];
#pragma unroll
    for (int f = 0; f < 12; f++) {
        const float sc = (f < 8) ? -LOG2E : 2.0f * LOG2E;
        int row = frow[f] + bi16;
        const float* src; int kin;
        if (fchk[f] == 0) { src = Wi + (size_t)row * wistride; kin = wistride; }
        else              { src = Wh + (size_t)row * HH;       kin = HH; }
        int wloidx = (f < 8) ? (f >> 1) : (f - 6);
#pragma unroll
        for (int kk = 0; kk < 8; kk++) {
            int k = quad * 8 + kk;
            float v = (k < kin) ? src[k] * sc : 0.0f;
            _Float16 h = (_Float16)v;
            Whi[f][kk] = h;
            if (fchk[f] == 1) Wlo[wloidx][kk] = (_Float16)(v - (float)h);
        }
    }

    // ---- biases in registers (pre-scaled, per C-tile f32x4) ----
    f32x4 biasreg[8];
#pragma unroll
    for (int ct = 0; ct < 8; ct++) {
        int g = ct >> 1, jt = ct & 1;
#pragma unroll
        for (int r = 0; r < 4; r++) {
            int j = jt * 16 + quad * 4 + r;
            float v;
            if      (g == 0) v = -(bivec[j]      + bhvec[j])      * LOG2E;
            else if (g == 1) v = -(bivec[32 + j] + bhvec[32 + j]) * LOG2E;
            else if (g == 2) v = bivec[64 + j] * (2.0f * LOG2E);
            else             v = bhvec[64 + j] * (2.0f * LOG2E);
            biasreg[ct][r] = v;
        }
    }

    int capT = -1;   // last-layer capture timestep (waves 10,11)
    if (w >= 10) {
        int len = lengths[bg * 16 + bi16];
        capT = ((len < 1) ? 1 : len) - 1;
    }

    const int laneoff = lane * 8;
    const int inbase  = (layer == 0) ? X_HI : (H_HI + (layer - 1) * 4096);
    const int inmask  = (layer == 0) ? 3 : 7;
    const int ownhi   = H_HI + layer * 4096;
    const int ownlo   = H_LO + layer * 1024;
    const int wibase  = (quad >> 1) * 128 + bi16 * 8 + (quad & 1) * 4;

    // x staging constants (wave 0, lanes 0-47)
    const int xbb = lane / 3, xkg = lane - xbb * 3;
    const int xq   = (xkg == 2) ? 1 : 0;
    const int xoff = (xkg == 1) ? 4 : 0;
    const int xidx = xq * 128 + xbb * 8 + xoff;
    const bool xlane = (w == 0) && (lane < 48);

    auto stage_x = [&](const float4& xl, int t) {
        half4 h4;
        h4[0] = (_Float16)xl.x; h4[1] = (_Float16)xl.y;
        h4[2] = (_Float16)xl.z; h4[3] = (_Float16)xl.w;
        *(half4*)(lds16 + X_HI + ((t & 3) << 9) + xidx) = h4;
    };

    // stage x[0], x[1]
    if (xlane) {
        float4 x0 = *(const float4*)(x + (size_t)bg * 192 + lane * 4);
        float4 x1 = *(const float4*)(x + (size_t)BB * IN_DIM + (size_t)bg * 192 + lane * 4);
        stage_x(x0, 0);
        stage_x(x1, 1);
    }

    f32x2 hprev[4];   // hprev[jt*2+pr]; halves use only jt == myjt entries
#pragma unroll
    for (int i = 0; i < 4; i++) { hprev[i][0] = 0.0f; hprev[i][1] = 0.0f; }

    __syncthreads();   // flags + h0 + x0/x1 visible before self-timed phase

    auto substep = [&](int t) {
        // sibling handshake (split layers): need sibling's h(t-1) half
        if (isHalf) {
            while (__hip_atomic_load(&sibF[(w ^ 1) - 8], __ATOMIC_ACQUIRE,
                                     __HIP_MEMORY_SCOPE_WORKGROUP) < t - 1)
                __builtin_amdgcn_s_sleep(1);
        }

        // B-fragments: input (f16 hi only) + own h (hi+lo, full K)
        half8 bxh = *(const half8*)(lds16 + inbase + ((t & inmask) << 9) + laneoff);
        half8 bhh = *(const half8*)(lds16 + ownhi + (((t + 7) & 7) << 9) + laneoff);
        half8 bhl = *(const half8*)(lds16 + ownlo + (((t + 1) & 1) << 9) + laneoff);

        f32x4 acc[8];

        // MFMAs (full: 24; half: 12). Bias folded into first C operand.
#pragma unroll
        for (int ct = 0; ct < 4; ct++) {
            if (!isHalf || (ct & 1) == myjt) {
                acc[ct] = __builtin_amdgcn_mfma_f32_16x16x32_f16(
                              Whi[ct * 2 + 0], bxh, biasreg[ct], 0, 0, 0);
                MFMA_(Whi[ct * 2 + 1], bhh, acc[ct]);
                MFMA_(Whi[ct * 2 + 1], bhl, acc[ct]);
                MFMA_(Wlo[ct],         bhh, acc[ct]);
            }
        }
#pragma unroll
        for (int jt = 0; jt < 2; jt++) {
            if (!isHalf || jt == myjt) {
                acc[4 + jt] = __builtin_amdgcn_mfma_f32_16x16x32_f16(
                                  Whi[8 + jt], bxh, biasreg[4 + jt], 0, 0, 0);
                acc[6 + jt] = __builtin_amdgcn_mfma_f32_16x16x32_f16(
                                  Whi[10 + jt], bhh, biasreg[6 + jt], 0, 0, 0);
                MFMA_(Whi[10 + jt], bhl, acc[6 + jt]);
                MFMA_(Wlo[4 + jt],  bhh, acc[6 + jt]);
            }
        }

        // Epilogue, f32x2-packed over row pairs; batched rcp.
#pragma unroll
        for (int jt = 0; jt < 2; jt++) {
            if (isHalf && jt != myjt) continue;
            half4 h4, l4;
            float hv[4];
#pragma unroll
            for (int pr = 0; pr < 2; pr++) {
                f32x2 R2, Z2, I2, H2;
                R2[0] = acc[0 + jt][2 * pr]; R2[1] = acc[0 + jt][2 * pr + 1];
                Z2[0] = acc[2 + jt][2 * pr]; Z2[1] = acc[2 + jt][2 * pr + 1];
                I2[0] = acc[4 + jt][2 * pr]; I2[1] = acc[4 + jt][2 * pr + 1];
                H2[0] = acc[6 + jt][2 * pr]; H2[1] = acc[6 + jt][2 * pr + 1];
                f32x2 av, bv;
                av[0] = __builtin_amdgcn_exp2f(R2[0]);
                av[1] = __builtin_amdgcn_exp2f(R2[1]);
                bv[0] = __builtin_amdgcn_exp2f(Z2[0]);
                bv[1] = __builtin_amdgcn_exp2f(Z2[1]);
                av = av + 1.0f;                       // pk_add
                bv = bv + 1.0f;
                f32x2 pv = av * bv;                   // pk_mul
                float q  = __builtin_amdgcn_rcpf(pv[0] * pv[1]);
                f32x2 qs; qs[0] = q * pv[1]; qs[1] = q * pv[0];   // 1/p0, 1/p1
                f32x2 rv = qs * bv;                   // = 1/a
                f32x2 zv = qs * av;                   // = 1/b
                f32x2 na = __builtin_elementwise_fma(rv, H2, I2);
                f32x2 ea;
                ea[0] = __builtin_amdgcn_exp2f(na[0]);
                ea[1] = __builtin_amdgcn_exp2f(na[1]);
                f32x2 dv = ea + 1.0f;
                float qn = __builtin_amdgcn_rcpf(dv[0] * dv[1]);
                f32x2 qv; qv[0] = qn * dv[1]; qv[1] = qn * dv[0]; // 1/d0, 1/d1
                f32x2 m2; m2[0] = -2.0f; m2[1] = -2.0f;
                f32x2 o1; o1[0] = 1.0f;  o1[1] = 1.0f;
                f32x2 nv = __builtin_elementwise_fma(m2, qv, o1);
                f32x2 hp = hprev[jt * 2 + pr];
                f32x2 hn = __builtin_elementwise_fma(zv, hp - nv, nv);
                hprev[jt * 2 + pr] = hn;
                _Float16 hh0 = (_Float16)hn[0], hh1 = (_Float16)hn[1];
                f32x2 hi32; hi32[0] = (float)hh0; hi32[1] = (float)hh1;
                f32x2 lo2 = hn - hi32;               // pk_sub
                h4[2 * pr]     = hh0; h4[2 * pr + 1] = hh1;
                l4[2 * pr]     = (_Float16)lo2[0];
                l4[2 * pr + 1] = (_Float16)lo2[1];
                hv[2 * pr]     = hn[0];
                hv[2 * pr + 1] = hn[1];
            }
            int wi = jt * 256 + wibase;
            *(half4*)(lds16 + ownhi + ((t & 7) << 9) + wi) = h4;
            *(half4*)(lds16 + ownlo + ((t & 1) << 9) + wi) = l4;
            if (w >= 10 && t == capT) {
                float4 o = make_float4(hv[0], hv[1], hv[2], hv[3]);
                *(float4*)(last + (size_t)(bg * 16 + bi16) * HH + jt * 16 + quad * 4) = o;
            }
        }

        // sibling publish (release drains the h4/l4 DS writes)
        if (isHalf && lane == 0) {
            __hip_atomic_store(&sibF[w - 8], t, __ATOMIC_RELEASE,
                               __HIP_MEMORY_SCOPE_WORKGROUP);
        }
    };

    for (int t = 0; t < TT; t += 2) {
        // ---- fwd sync: input panels for t, t+1 must be published ----
        if (w >= 1 && w <= 7) {
            while (__hip_atomic_load(&flagS[w - 1], __ATOMIC_ACQUIRE,
                                     __HIP_MEMORY_SCOPE_WORKGROUP) < t + 1)
                __builtin_amdgcn_s_sleep(1);
        } else if (w == 8 || w == 9) {
            while (__hip_atomic_load(&flagS[7], __ATOMIC_ACQUIRE,
                                     __HIP_MEMORY_SCOPE_WORKGROUP) < t + 1)
                __builtin_amdgcn_s_sleep(1);
        } else if (w >= 10) {
            while (__hip_atomic_load(&flagS[8], __ATOMIC_ACQUIRE,
                                     __HIP_MEMORY_SCOPE_WORKGROUP) < t + 1)
                __builtin_amdgcn_s_sleep(1);
            while (__hip_atomic_load(&flagS[9], __ATOMIC_ACQUIRE,
                                     __HIP_MEMORY_SCOPE_WORKGROUP) < t + 1)
                __builtin_amdgcn_s_sleep(1);
        }
        // ---- bwd sync: writing t+1 reuses slot of t-7 ----
        if (w <= 6) {
            while (__hip_atomic_load(&rflagS[w + 1], __ATOMIC_ACQUIRE,
                                     __HIP_MEMORY_SCOPE_WORKGROUP) < t - 7)
                __builtin_amdgcn_s_sleep(1);
        } else if (w == 7) {
            while (__hip_atomic_load(&rflagS[8], __ATOMIC_ACQUIRE,
                                     __HIP_MEMORY_SCOPE_WORKGROUP) < t - 7)
                __builtin_amdgcn_s_sleep(1);
            while (__hip_atomic_load(&rflagS[9], __ATOMIC_ACQUIRE,
                                     __HIP_MEMORY_SCOPE_WORKGROUP) < t - 7)
                __builtin_amdgcn_s_sleep(1);
        } else if (w == 8 || w == 9) {
            while (__hip_atomic_load(&rflagS[10], __ATOMIC_ACQUIRE,
                                     __HIP_MEMORY_SCOPE_WORKGROUP) < t - 7)
                __builtin_amdgcn_s_sleep(1);
            while (__hip_atomic_load(&rflagS[11], __ATOMIC_ACQUIRE,
                                     __HIP_MEMORY_SCOPE_WORKGROUP) < t - 7)
                __builtin_amdgcn_s_sleep(1);
        }

        // wave 0: issue global x loads for t+2, t+3 early
        float4 xa0, xa1;
        bool dl0 = false, dl1 = false;
        if (xlane) {
            if (t + 2 < TT) {
                xa0 = *(const float4*)(x + (size_t)(t + 2) * BB * IN_DIM +
                                       (size_t)bg * 192 + lane * 4);
                dl0 = true;
            }
            if (t + 3 < TT) {
                xa1 = *(const float4*)(x + (size_t)(t + 3) * BB * IN_DIM +
                                       (size_t)bg * 192 + lane * 4);
                dl1 = true;
            }
        }

        substep(t);
        substep(t + 1);

        if (dl0) stage_x(xa0, t + 2);   // 4 x-slots: no overlap with t, t+1
        if (dl1) stage_x(xa1, t + 3);

        if (lane == 0) {
            // release: drains this wave's DS ops before publishing
            if (w <= 9)
                __hip_atomic_store(&flagS[w], t + 1, __ATOMIC_RELEASE,
                                   __HIP_MEMORY_SCOPE_WORKGROUP);
            if (w >= 1)
                __hip_atomic_store(&rflagS[w], t + 1, __ATOMIC_RELEASE,
                                   __HIP_MEMORY_SCOPE_WORKGROUP);
        }
    }
}

__global__ __launch_bounds__(256)
void fc_head(const float* __restrict__ last,
             const float* __restrict__ fcW,   // [C][H]
             const float* __restrict__ fcb,   // [C]
             float* __restrict__ out)         // [B][C]
{
    int b = blockIdx.x * blockDim.x + threadIdx.x;
    if (b >= BB) return;
    float lg[CC];
#pragma unroll
    for (int c = 0; c < CC; c++) lg[c] = fcb[c];
#pragma unroll
    for (int j = 0; j < HH; j++) {
        float h = last[(size_t)b * HH + j];
#pragma unroll
        for (int c = 0; c < CC; c++) lg[c] = fmaf(fcW[c * HH + j], h, lg[c]);
    }
    float m = lg[0];
#pragma unroll
    for (int c = 1; c < CC; c++) m = fmaxf(m, lg[c]);
    float s = 0.0f;
#pragma unroll
    for (int c = 0; c < CC; c++) s += __expf(lg[c] - m);
    float lse = m + logf(s);
#pragma unroll
    for (int c = 0; c < CC; c++) out[(size_t)b * CC + c] = lg[c] - lse;
}

extern "C" void kernel_launch(void* const* d_in, const int* in_sizes, int n_in,
                              void* d_out, int out_size, void* d_ws, size_t ws_size,
                              hipStream_t stream)
{
    const float* x    = (const float*)d_in[0];
    const float* Wih0 = (const float*)d_in[1];
    const float* Whh0 = (const float*)d_in[2];
    const float* bih0 = (const float*)d_in[3];
    const float* bhh0 = (const float*)d_in[4];
    const float* Wih  = (const float*)d_in[5];
    const float* Whh  = (const float*)d_in[6];
    const float* bih  = (const float*)d_in[7];
    const float* bhh  = (const float*)d_in[8];
    const float* fcW  = (const float*)d_in[9];
    const float* fcb  = (const float*)d_in[10];
    const int*   lens = (const int*)d_in[11];
    float* out = (float*)d_out;

    float* last = (float*)d_ws;   // [B][32] = 512 KB

    gru_fused_mfma<<<dim3(BB / 16), dim3(NTH), 0, stream>>>(
        x, Wih0, Whh0, bih0, bhh0, Wih, Whh, bih, bhh, lens, last);

    fc_head<<<dim3(BB / 256), dim3(256), 0, stream>>>(last, fcW, fcb, out);
}

// Round 7
// 949.466 us; speedup vs baseline: 1.4813x; 1.4813x over previous
//
#include <hip/hip_runtime.h>
#include <math.h>

#define TT 512
#define BB 4096
#define IN_DIM 12
#define HH 32
#define LL 10
#define CC 4
#define NTH (LL * 64)        // 640 threads = 10 waves, one per layer

typedef _Float16 half8 __attribute__((ext_vector_type(8)));
typedef _Float16 half4 __attribute__((ext_vector_type(4)));
typedef float f32x4 __attribute__((ext_vector_type(4)));
typedef float f32x2 __attribute__((ext_vector_type(2)));

#define LOG2E 1.44269504088896340736f

// f16-unit offsets in the LDS arena (total 53248 f16 = 104 KB static):
//  H_HI: per-layer h hi panels, 8 slots (mod-8 of t) — cross-wave handoff
//  H_LO: per-layer h lo panels, 2 slots — own-layer recurrence
//  X_HI: wave-0 x panels, 4 slots — wave-internal
#define H_HI 0
#define H_LO (LL * 8 * 512)             // 40960
#define X_HI (H_LO + LL * 2 * 512)      // 51200
#define LDS16_TOT (X_HI + 4 * 512)      // 53248

#define MFMA_(A, B, C) C = __builtin_amdgcn_mfma_f32_16x16x32_f16(A, B, C, 0, 0, 0)

// Fused 10-layer GRU, temporal pipeline, MFMA cells, self-timed flags.
//
// Session ledger:
//  R1: batched-rcp ~neutral -> trans are cheap; VALUBusy includes MFMA.
//  R2: 4-wave multi-cell FAILED (VGPR 370 >> 196 -> serialized). TLP is
//      load-bearing.
//  R4/R5: pk-epilogue + 8-slot H_HI = -51us (952->901); s_setprio = -110us
//      HARM (starves co-resident epilogue VALU). BANNED here.
//  R6: M-split of L8/L9 FAILED (1406us): cross-wave handshake inside the
//      per-timestep recurrence costs ~2400cyc/substep on the slowest stage.
//      BANNED. {3,3,2,2} SIMD imbalance is pigeonhole-unavoidable.
//  R7 (this round), on the R5 base, issue-trimming only:
//   (a) t-loop unrolled x8 (4 pairs/superblock, sync protocol identical):
//       all LDS slot selectors become literal offset: immediates; base
//       addresses hoisted to loop-invariant VGPRs.
//   (b) fc_head folded in: capT h -> padded LDS (stride 33); after the
//       loop wave 0 computes logits + log_softmax (same per-(b,c) op
//       order; reductions commutative-exact) -> one kernel, no 'last'
//       global round-trip.
__global__ __launch_bounds__(NTH, 2)
void gru_fused_mfma(const float* __restrict__ x,      // [T][B][12]
                    const float* __restrict__ Wih0,   // [96][12]
                    const float* __restrict__ Whh0,   // [96][32]
                    const float* __restrict__ bih0,   // [96]
                    const float* __restrict__ bhh0,   // [96]
                    const float* __restrict__ Wih,    // [9][96][32]
                    const float* __restrict__ Whh,    // [9][96][32]
                    const float* __restrict__ bih,    // [9][96]
                    const float* __restrict__ bhh,    // [9][96]
                    const int*   __restrict__ lengths,
                    const float* __restrict__ fcW,    // [C][H]
                    const float* __restrict__ fcb,    // [C]
                    float*       __restrict__ out)    // [B][C]
{
    __shared__ __align__(16) _Float16 lds16[LDS16_TOT];
    __shared__ float lastF[16 * 33];   // capT h rows, stride 33 (bank-safe)
    __shared__ int flagS[LL];    // producer progress
    __shared__ int rflagS[LL];   // consumer progress (indexed by producer)

    const int tid  = threadIdx.x;
    const int w    = tid >> 6;      // layer
    const int lane = tid & 63;
    const int bi16 = lane & 15;     // batch col within group
    const int quad = lane >> 4;
    const int bg   = blockIdx.x;    // batch group (16 elems)

    // ---- zero the arena (h0 = 0, zero-padding) + init flags ----
    {
        float4 z4 = make_float4(0.f, 0.f, 0.f, 0.f);
        float4* p = (float4*)lds16;
        for (int i = tid; i < LDS16_TOT / 8; i += NTH) p[i] = z4;
    }
    if (lane == 0) { flagS[w] = -1; rflagS[w] = -1; }
    __syncthreads();

    // ---- per-wave weight pointers ----
    const float *Wi, *Wh, *bivec, *bhvec;
    int wistride;
    if (w == 0) { Wi = Wih0; Wh = Whh0; bivec = bih0; bhvec = bhh0; wistride = IN_DIM; }
    else {
        Wi = Wih + (size_t)(w - 1) * 96 * HH;
        Wh = Whh + (size_t)(w - 1) * 96 * HH;
        bivec = bih + (size_t)(w - 1) * 96;
        bhvec = bhh + (size_t)(w - 1) * 96;
        wistride = HH;
    }

    // ---- stationary A-fragments (pre-scaled) ----
    const int frow[12] = {0, 0, 16, 16, 32, 32, 48, 48, 64, 80, 64, 80};
    const int fchk[12] = {0, 1, 0, 1, 0, 1, 0, 1, 0, 0, 1, 1};
    half8 Whi[12], Wlo[6];
#pragma unroll
    for (int f = 0; f < 12; f++) {
        const float sc = (f < 8) ? -LOG2E : 2.0f * LOG2E;
        int row = frow[f] + bi16;
        const float* src; int kin;
        if (fchk[f] == 0) { src = Wi + (size_t)row * wistride; kin = wistride; }
        else              { src = Wh + (size_t)row * HH;       kin = HH; }
        int wloidx = (f < 8) ? (f >> 1) : (f - 6);
#pragma unroll
        for (int kk = 0; kk < 8; kk++) {
            int k = quad * 8 + kk;
            float v = (k < kin) ? src[k] * sc : 0.0f;
            _Float16 h = (_Float16)v;
            Whi[f][kk] = h;
            if (fchk[f] == 1) Wlo[wloidx][kk] = (_Float16)(v - (float)h);
        }
    }

    // ---- biases in registers (pre-scaled, per C-tile f32x4) ----
    f32x4 biasreg[8];
#pragma unroll
    for (int ct = 0; ct < 8; ct++) {
        int g = ct >> 1, jt = ct & 1;
#pragma unroll
        for (int r = 0; r < 4; r++) {
            int j = jt * 16 + quad * 4 + r;
            float v;
            if      (g == 0) v = -(bivec[j]      + bhvec[j])      * LOG2E;
            else if (g == 1) v = -(bivec[32 + j] + bhvec[32 + j]) * LOG2E;
            else if (g == 2) v = bivec[64 + j] * (2.0f * LOG2E);
            else             v = bhvec[64 + j] * (2.0f * LOG2E);
            biasreg[ct][r] = v;
        }
    }

    int capT = -1;   // last-layer capture timestep per lane
    if (w == LL - 1) {
        int len = lengths[bg * 16 + bi16];
        capT = ((len < 1) ? 1 : len) - 1;
    }

    const int laneoff = lane * 8;
    const int inbase  = (w == 0) ? X_HI : (H_HI + (w - 1) * 4096);
    const int inmask  = (w == 0) ? 3 : 7;
    const int wibase  = (quad >> 1) * 128 + bi16 * 8 + (quad & 1) * 4;

    // loop-invariant LDS addresses (slot selection via literal offsets)
    const int inA   = inbase + laneoff;                 // + ((k&inmask)<<9)
    const int hiR   = H_HI + w * 4096 + laneoff;        // + (((k+7)&7)<<9)
    const int loR   = H_LO + w * 1024 + laneoff;        // + (((k+1)&1)<<9)
    const int hiW   = H_HI + w * 4096 + wibase;         // + ((k&7)<<9) + jt*256
    const int loW   = H_LO + w * 1024 + wibase;         // + ((k&1)<<9) + jt*256

    // x staging constants (wave 0, lanes 0-47)
    const int xbb = lane / 3, xkg = lane - xbb * 3;
    const int xq   = (xkg == 2) ? 1 : 0;
    const int xoff = (xkg == 1) ? 4 : 0;
    const int xidx = xq * 128 + xbb * 8 + xoff;
    const bool xlane = (w == 0) && (lane < 48);

    auto stage_x = [&](const float4& xl, int slot) {   // slot = literal
        half4 h4;
        h4[0] = (_Float16)xl.x; h4[1] = (_Float16)xl.y;
        h4[2] = (_Float16)xl.z; h4[3] = (_Float16)xl.w;
        *(half4*)(lds16 + X_HI + (slot << 9) + xidx) = h4;
    };

    // stage x[0], x[1]
    if (xlane) {
        float4 x0 = *(const float4*)(x + (size_t)bg * 192 + lane * 4);
        float4 x1 = *(const float4*)(x + (size_t)BB * IN_DIM + (size_t)bg * 192 + lane * 4);
        stage_x(x0, 0);
        stage_x(x1, 1);
    }

    f32x2 hprev[4];   // hprev[jt*2+pr] = rows (2pr, 2pr+1) of jt-half
#pragma unroll
    for (int i = 0; i < 4; i++) { hprev[i][0] = 0.0f; hprev[i][1] = 0.0f; }

    __syncthreads();   // flags + h0 + x0/x1 visible before self-timed phase

    // one substep; k = t mod 8, arrives as a literal -> slot immediates
    auto substep = [&](int t, int k) {
        half8 bxh = *(const half8*)(lds16 + inA + ((k & inmask) << 9));
        half8 bhh = *(const half8*)(lds16 + hiR + (((k + 7) & 7) << 9));
        half8 bhl = *(const half8*)(lds16 + loR + (((k + 1) & 1) << 9));

        f32x4 acc[8];

        // 24 MFMAs: r/z tiles 4 each; IN 1 each; HN 3 each.
#pragma unroll
        for (int ct = 0; ct < 4; ct++) {
            acc[ct] = __builtin_amdgcn_mfma_f32_16x16x32_f16(
                          Whi[ct * 2 + 0], bxh, biasreg[ct], 0, 0, 0);
            MFMA_(Whi[ct * 2 + 1], bhh, acc[ct]);
            MFMA_(Whi[ct * 2 + 1], bhl, acc[ct]);
            MFMA_(Wlo[ct],         bhh, acc[ct]);
        }
#pragma unroll
        for (int jt = 0; jt < 2; jt++) {
            acc[4 + jt] = __builtin_amdgcn_mfma_f32_16x16x32_f16(
                              Whi[8 + jt], bxh, biasreg[4 + jt], 0, 0, 0);
            acc[6 + jt] = __builtin_amdgcn_mfma_f32_16x16x32_f16(
                              Whi[10 + jt], bhh, biasreg[6 + jt], 0, 0, 0);
            MFMA_(Whi[10 + jt], bhl, acc[6 + jt]);
            MFMA_(Wlo[4 + jt],  bhh, acc[6 + jt]);
        }

        // Epilogue, f32x2-packed over row pairs; batched rcp.
#pragma unroll
        for (int jt = 0; jt < 2; jt++) {
            half4 h4, l4;
            float hv[4];
#pragma unroll
            for (int pr = 0; pr < 2; pr++) {
                f32x2 R2, Z2, I2, H2;
                R2[0] = acc[0 + jt][2 * pr]; R2[1] = acc[0 + jt][2 * pr + 1];
                Z2[0] = acc[2 + jt][2 * pr]; Z2[1] = acc[2 + jt][2 * pr + 1];
                I2[0] = acc[4 + jt][2 * pr]; I2[1] = acc[4 + jt][2 * pr + 1];
                H2[0] = acc[6 + jt][2 * pr]; H2[1] = acc[6 + jt][2 * pr + 1];
                f32x2 av, bv;
                av[0] = __builtin_amdgcn_exp2f(R2[0]);
                av[1] = __builtin_amdgcn_exp2f(R2[1]);
                bv[0] = __builtin_amdgcn_exp2f(Z2[0]);
                bv[1] = __builtin_amdgcn_exp2f(Z2[1]);
                av = av + 1.0f;                       // pk_add
                bv = bv + 1.0f;
                f32x2 pv = av * bv;                   // pk_mul
                float q  = __builtin_amdgcn_rcpf(pv[0] * pv[1]);
                f32x2 qs; qs[0] = q * pv[1]; qs[1] = q * pv[0];   // 1/p0, 1/p1
                f32x2 rv = qs * bv;                   // = 1/a
                f32x2 zv = qs * av;                   // = 1/b
                f32x2 na = __builtin_elementwise_fma(rv, H2, I2);
                f32x2 ea;
                ea[0] = __builtin_amdgcn_exp2f(na[0]);
                ea[1] = __builtin_amdgcn_exp2f(na[1]);
                f32x2 dv = ea + 1.0f;
                float qn = __builtin_amdgcn_rcpf(dv[0] * dv[1]);
                f32x2 qv; qv[0] = qn * dv[1]; qv[1] = qn * dv[0]; // 1/d0, 1/d1
                f32x2 m2; m2[0] = -2.0f; m2[1] = -2.0f;
                f32x2 o1; o1[0] = 1.0f;  o1[1] = 1.0f;
                f32x2 nv = __builtin_elementwise_fma(m2, qv, o1);
                f32x2 hp = hprev[jt * 2 + pr];
                f32x2 hn = __builtin_elementwise_fma(zv, hp - nv, nv);
                hprev[jt * 2 + pr] = hn;
                _Float16 hh0 = (_Float16)hn[0], hh1 = (_Float16)hn[1];
                f32x2 hi32; hi32[0] = (float)hh0; hi32[1] = (float)hh1;
                f32x2 lo2 = hn - hi32;               // pk_sub
                h4[2 * pr]     = hh0; h4[2 * pr + 1] = hh1;
                l4[2 * pr]     = (_Float16)lo2[0];
                l4[2 * pr + 1] = (_Float16)lo2[1];
                hv[2 * pr]     = hn[0];
                hv[2 * pr + 1] = hn[1];
            }
            *(half4*)(lds16 + hiW + ((k & 7) << 9) + jt * 256) = h4;
            *(half4*)(lds16 + loW + ((k & 1) << 9) + jt * 256) = l4;
            if (w == LL - 1 && t == capT) {
                lastF[bi16 * 33 + jt * 16 + quad * 4 + 0] = hv[0];
                lastF[bi16 * 33 + jt * 16 + quad * 4 + 1] = hv[1];
                lastF[bi16 * 33 + jt * 16 + quad * 4 + 2] = hv[2];
                lastF[bi16 * 33 + jt * 16 + quad * 4 + 3] = hv[3];
            }
        }
    };

    // one pair; kp is a LITERAL (0,2,4,6) -> all slot math folds
#define PAIR(kp)                                                          \
    do {                                                                  \
        const int t = tb + (kp);                                          \
        if (w > 0) {                                                      \
            while (__hip_atomic_load(&flagS[w - 1], __ATOMIC_ACQUIRE,     \
                                     __HIP_MEMORY_SCOPE_WORKGROUP) < t + 1)\
                __builtin_amdgcn_s_sleep(1);                              \
        }                                                                 \
        if (w < LL - 1) {                                                 \
            while (__hip_atomic_load(&rflagS[w], __ATOMIC_ACQUIRE,        \
                                     __HIP_MEMORY_SCOPE_WORKGROUP) < t - 7)\
                __builtin_amdgcn_s_sleep(1);                              \
        }                                                                 \
        float4 xa0, xa1;                                                  \
        bool dl0 = false, dl1 = false;                                    \
        if (xlane) {                                                      \
            if (t + 2 < TT) {                                             \
                xa0 = *(const float4*)(x + (size_t)(t + 2) * BB * IN_DIM +\
                                       (size_t)bg * 192 + lane * 4);      \
                dl0 = true;                                               \
            }                                                             \
            if (t + 3 < TT) {                                             \
                xa1 = *(const float4*)(x + (size_t)(t + 3) * BB * IN_DIM +\
                                       (size_t)bg * 192 + lane * 4);      \
                dl1 = true;                                               \
            }                                                             \
        }                                                                 \
        substep(t, (kp));                                                 \
        substep(t + 1, (kp) + 1);                                         \
        if (dl0) stage_x(xa0, ((kp) + 2) & 3);                            \
        if (dl1) stage_x(xa1, ((kp) + 3) & 3);                            \
        if (lane == 0) {                                                  \
            if (w < LL - 1)                                               \
                __hip_atomic_store(&flagS[w], t + 1, __ATOMIC_RELEASE,    \
                                   __HIP_MEMORY_SCOPE_WORKGROUP);         \
            if (w > 0)                                                    \
                __hip_atomic_store(&rflagS[w - 1], t + 1, __ATOMIC_RELEASE,\
                                   __HIP_MEMORY_SCOPE_WORKGROUP);         \
        }                                                                 \
    } while (0)

    for (int tb = 0; tb < TT; tb += 8) {
        PAIR(0);
        PAIR(2);
        PAIR(4);
        PAIR(6);
    }
#undef PAIR

    // ---- fused FC head: wave 0 computes logits + log_softmax ----
    __syncthreads();   // lastF complete (capT <= TT-1 < loop end)
    if (w == 0) {
        const int b = lane & 15;     // batch col
        const int c = lane >> 4;     // class
        float lg = fcb[c];
#pragma unroll
        for (int j = 0; j < HH; j++)
            lg = fmaf(fcW[c * HH + j], lastF[b * 33 + j], lg);
        float m = fmaxf(lg, __shfl_xor(lg, 16));
        m = fmaxf(m, __shfl_xor(m, 32));
        float e = __expf(lg - m);
        float s = e + __shfl_xor(e, 16);
        s += __shfl_xor(s, 32);
        float lse = m + logf(s);
        out[(size_t)(bg * 16 + b) * CC + c] = lg - lse;
    }
}

extern "C" void kernel_launch(void* const* d_in, const int* in_sizes, int n_in,
                              void* d_out, int out_size, void* d_ws, size_t ws_size,
                              hipStream_t stream)
{
    const float* x    = (const float*)d_in[0];
    const float* Wih0 = (const float*)d_in[1];
    const float* Whh0 = (const float*)d_in[2];
    const float* bih0 = (const float*)d_in[3];
    const float* bhh0 = (const float*)d_in[4];
    const float* Wih  = (const float*)d_in[5];
    const float* Whh  = (const float*)d_in[6];
    const float* bih  = (const float*)d_in[7];
    const float* bhh  = (const float*)d_in[8];
    const float* fcW  = (const float*)d_in[9];
    const float* fcb  = (const float*)d_in[10];
    const int*   lens = (const int*)d_in[11];
    float* out = (float*)d_out;

    gru_fused_mfma<<<dim3(BB / 16), dim3(NTH), 0, stream>>>(
        x, Wih0, Whh0, bih0, bhh0, Wih, Whh, bih, bhh, lens, fcW, fcb, out);
}

// Round 8
// 907.053 us; speedup vs baseline: 1.5506x; 1.0468x over previous
//
#include <hip/hip_runtime.h>
#include <math.h>

#define TT 512
#define BB 4096
#define IN_DIM 12
#define HH 32
#define LL 10
#define CC 4
#define NTH (LL * 64)        // 640 threads = 10 waves, one per layer

typedef _Float16 half8 __attribute__((ext_vector_type(8)));
typedef _Float16 half4 __attribute__((ext_vector_type(4)));
typedef float f32x4 __attribute__((ext_vector_type(4)));
typedef float f32x2 __attribute__((ext_vector_type(2)));

#define LOG2E 1.44269504088896340736f

// f16-unit offsets in the LDS arena (total 53248 f16 = 104 KB static):
//  H_HI: per-layer h hi panels, 8 slots (mod-8 of t) — cross-wave handoff
//  H_LO: per-layer h lo panels, 2 slots — own-layer recurrence
//  X_HI: wave-0 x panels, 4 slots — wave-internal
#define H_HI 0
#define H_LO (LL * 8 * 512)             // 40960
#define X_HI (H_LO + LL * 2 * 512)      // 51200
#define LDS16_TOT (X_HI + 4 * 512)      // 53248

#define MFMA_(A, B, C) C = __builtin_amdgcn_mfma_f32_16x16x32_f16(A, B, C, 0, 0, 0)

// Fused 10-layer GRU, temporal pipeline, MFMA cells, self-timed flags.
//
// Session ledger:
//  R1: batched-rcp ~neutral -> trans are cheap; VALUBusy includes MFMA.
//  R2: 4-wave multi-cell FAILED (VGPR 370 >> 196 -> serialized). TLP is
//      load-bearing.
//  R4/R5: pk-epilogue + 8-slot H_HI = -51us (952->901); s_setprio = -110us
//      HARM (starves co-resident epilogue VALU). BANNED here.
//  R6: M-split of L8/L9 FAILED (1406us): cross-wave handshake inside the
//      per-timestep recurrence. BANNED. {3,3,2,2} imbalance unavoidable.
//  R7: x8 unroll FAILED (+48us): ~10KB loop body -> I-fetch pressure
//      (FETCH +2.5MB, VALUBusy down but period up). Unroll BANNED.
//  R8 (this round): R5 base + fc_head fused only (single variable).
//      capT h -> padded LDS (stride 33); after the loop wave 0 computes
//      logits + log_softmax. Removes the 2nd launch and the 'last'
//      global round-trip. Numerics identical (validated in R7).
__global__ __launch_bounds__(NTH, 2)
void gru_fused_mfma(const float* __restrict__ x,      // [T][B][12]
                    const float* __restrict__ Wih0,   // [96][12]
                    const float* __restrict__ Whh0,   // [96][32]
                    const float* __restrict__ bih0,   // [96]
                    const float* __restrict__ bhh0,   // [96]
                    const float* __restrict__ Wih,    // [9][96][32]
                    const float* __restrict__ Whh,    // [9][96][32]
                    const float* __restrict__ bih,    // [9][96]
                    const float* __restrict__ bhh,    // [9][96]
                    const int*   __restrict__ lengths,
                    const float* __restrict__ fcW,    // [C][H]
                    const float* __restrict__ fcb,    // [C]
                    float*       __restrict__ out)    // [B][C]
{
    __shared__ __align__(16) _Float16 lds16[LDS16_TOT];
    __shared__ float lastF[16 * 33];   // capT h rows, stride 33 (bank-safe)
    __shared__ int flagS[LL];    // producer progress
    __shared__ int rflagS[LL];   // consumer progress (indexed by producer)

    const int tid  = threadIdx.x;
    const int w    = tid >> 6;      // layer
    const int lane = tid & 63;
    const int bi16 = lane & 15;     // batch col within group
    const int quad = lane >> 4;
    const int bg   = blockIdx.x;    // batch group (16 elems)

    // ---- zero the arena (h0 = 0, zero-padding) + init flags ----
    {
        float4 z4 = make_float4(0.f, 0.f, 0.f, 0.f);
        float4* p = (float4*)lds16;
        for (int i = tid; i < LDS16_TOT / 8; i += NTH) p[i] = z4;
    }
    if (lane == 0) { flagS[w] = -1; rflagS[w] = -1; }
    __syncthreads();

    // ---- per-wave weight pointers ----
    const float *Wi, *Wh, *bivec, *bhvec;
    int wistride;
    if (w == 0) { Wi = Wih0; Wh = Whh0; bivec = bih0; bhvec = bhh0; wistride = IN_DIM; }
    else {
        Wi = Wih + (size_t)(w - 1) * 96 * HH;
        Wh = Whh + (size_t)(w - 1) * 96 * HH;
        bivec = bih + (size_t)(w - 1) * 96;
        bhvec = bhh + (size_t)(w - 1) * 96;
        wistride = HH;
    }

    // ---- stationary A-fragments (pre-scaled) ----
    const int frow[12] = {0, 0, 16, 16, 32, 32, 48, 48, 64, 80, 64, 80};
    const int fchk[12] = {0, 1, 0, 1, 0, 1, 0, 1, 0, 0, 1, 1};
    half8 Whi[12], Wlo[6];
#pragma unroll
    for (int f = 0; f < 12; f++) {
        const float sc = (f < 8) ? -LOG2E : 2.0f * LOG2E;
        int row = frow[f] + bi16;
        const float* src; int kin;
        if (fchk[f] == 0) { src = Wi + (size_t)row * wistride; kin = wistride; }
        else              { src = Wh + (size_t)row * HH;       kin = HH; }
        int wloidx = (f < 8) ? (f >> 1) : (f - 6);
#pragma unroll
        for (int kk = 0; kk < 8; kk++) {
            int k = quad * 8 + kk;
            float v = (k < kin) ? src[k] * sc : 0.0f;
            _Float16 h = (_Float16)v;
            Whi[f][kk] = h;
            if (fchk[f] == 1) Wlo[wloidx][kk] = (_Float16)(v - (float)h);
        }
    }

    // ---- biases in registers (pre-scaled, per C-tile f32x4) ----
    f32x4 biasreg[8];
#pragma unroll
    for (int ct = 0; ct < 8; ct++) {
        int g = ct >> 1, jt = ct & 1;
#pragma unroll
        for (int r = 0; r < 4; r++) {
            int j = jt * 16 + quad * 4 + r;
            float v;
            if      (g == 0) v = -(bivec[j]      + bhvec[j])      * LOG2E;
            else if (g == 1) v = -(bivec[32 + j] + bhvec[32 + j]) * LOG2E;
            else if (g == 2) v = bivec[64 + j] * (2.0f * LOG2E);
            else             v = bhvec[64 + j] * (2.0f * LOG2E);
            biasreg[ct][r] = v;
        }
    }

    int capT = -1;   // last-layer capture timestep per lane
    if (w == LL - 1) {
        int len = lengths[bg * 16 + bi16];
        capT = ((len < 1) ? 1 : len) - 1;
    }

    const int laneoff = lane * 8;
    const int inbase  = (w == 0) ? X_HI : (H_HI + (w - 1) * 4096);
    const int inmask  = (w == 0) ? 3 : 7;
    const int ownhi   = H_HI + w * 4096;
    const int ownlo   = H_LO + w * 1024;
    const int wibase  = (quad >> 1) * 128 + bi16 * 8 + (quad & 1) * 4;

    // x staging constants (wave 0, lanes 0-47)
    const int xbb = lane / 3, xkg = lane - xbb * 3;
    const int xq   = (xkg == 2) ? 1 : 0;
    const int xoff = (xkg == 1) ? 4 : 0;
    const int xidx = xq * 128 + xbb * 8 + xoff;
    const bool xlane = (w == 0) && (lane < 48);

    auto stage_x = [&](const float4& xl, int t) {
        half4 h4;
        h4[0] = (_Float16)xl.x; h4[1] = (_Float16)xl.y;
        h4[2] = (_Float16)xl.z; h4[3] = (_Float16)xl.w;
        *(half4*)(lds16 + X_HI + ((t & 3) << 9) + xidx) = h4;
    };

    // stage x[0], x[1]
    if (xlane) {
        float4 x0 = *(const float4*)(x + (size_t)bg * 192 + lane * 4);
        float4 x1 = *(const float4*)(x + (size_t)BB * IN_DIM + (size_t)bg * 192 + lane * 4);
        stage_x(x0, 0);
        stage_x(x1, 1);
    }

    f32x2 hprev[4];   // hprev[jt*2+pr] = rows (2pr, 2pr+1) of jt-half
#pragma unroll
    for (int i = 0; i < 4; i++) { hprev[i][0] = 0.0f; hprev[i][1] = 0.0f; }

    __syncthreads();   // flags + h0 + x0/x1 visible before self-timed phase

    auto substep = [&](int t) {
        // B-fragments: input (f16 hi only) + own h (hi+lo)
        half8 bxh = *(const half8*)(lds16 + inbase + ((t & inmask) << 9) + laneoff);
        half8 bhh = *(const half8*)(lds16 + ownhi + (((t + 7) & 7) << 9) + laneoff);
        half8 bhl = *(const half8*)(lds16 + ownlo + (((t + 1) & 1) << 9) + laneoff);

        f32x4 acc[8];

        // 24 MFMAs: r/z tiles 4 each; IN 1 each; HN 3 each.
        // First MFMA of each tile takes biasreg as the C operand directly.
#pragma unroll
        for (int ct = 0; ct < 4; ct++) {
            acc[ct] = __builtin_amdgcn_mfma_f32_16x16x32_f16(
                          Whi[ct * 2 + 0], bxh, biasreg[ct], 0, 0, 0);
            MFMA_(Whi[ct * 2 + 1], bhh, acc[ct]);
            MFMA_(Whi[ct * 2 + 1], bhl, acc[ct]);
            MFMA_(Wlo[ct],         bhh, acc[ct]);
        }
#pragma unroll
        for (int jt = 0; jt < 2; jt++) {
            acc[4 + jt] = __builtin_amdgcn_mfma_f32_16x16x32_f16(
                              Whi[8 + jt], bxh, biasreg[4 + jt], 0, 0, 0);
            acc[6 + jt] = __builtin_amdgcn_mfma_f32_16x16x32_f16(
                              Whi[10 + jt], bhh, biasreg[6 + jt], 0, 0, 0);
            MFMA_(Whi[10 + jt], bhl, acc[6 + jt]);
            MFMA_(Wlo[4 + jt],  bhh, acc[6 + jt]);
        }

        // Epilogue, f32x2-packed over row pairs; batched rcp.
#pragma unroll
        for (int jt = 0; jt < 2; jt++) {
            half4 h4, l4;
            float hv[4];
#pragma unroll
            for (int pr = 0; pr < 2; pr++) {
                f32x2 R2, Z2, I2, H2;
                R2[0] = acc[0 + jt][2 * pr]; R2[1] = acc[0 + jt][2 * pr + 1];
                Z2[0] = acc[2 + jt][2 * pr]; Z2[1] = acc[2 + jt][2 * pr + 1];
                I2[0] = acc[4 + jt][2 * pr]; I2[1] = acc[4 + jt][2 * pr + 1];
                H2[0] = acc[6 + jt][2 * pr]; H2[1] = acc[6 + jt][2 * pr + 1];
                f32x2 av, bv;
                av[0] = __builtin_amdgcn_exp2f(R2[0]);
                av[1] = __builtin_amdgcn_exp2f(R2[1]);
                bv[0] = __builtin_amdgcn_exp2f(Z2[0]);
                bv[1] = __builtin_amdgcn_exp2f(Z2[1]);
                av = av + 1.0f;                       // pk_add
                bv = bv + 1.0f;
                f32x2 pv = av * bv;                   // pk_mul
                float q  = __builtin_amdgcn_rcpf(pv[0] * pv[1]);
                f32x2 qs; qs[0] = q * pv[1]; qs[1] = q * pv[0];   // 1/p0, 1/p1
                f32x2 rv = qs * bv;                   // = 1/a
                f32x2 zv = qs * av;                   // = 1/b
                f32x2 na = __builtin_elementwise_fma(rv, H2, I2);
                f32x2 ea;
                ea[0] = __builtin_amdgcn_exp2f(na[0]);
                ea[1] = __builtin_amdgcn_exp2f(na[1]);
                f32x2 dv = ea + 1.0f;
                float qn = __builtin_amdgcn_rcpf(dv[0] * dv[1]);
                f32x2 qv; qv[0] = qn * dv[1]; qv[1] = qn * dv[0]; // 1/d0, 1/d1
                f32x2 m2; m2[0] = -2.0f; m2[1] = -2.0f;
                f32x2 o1; o1[0] = 1.0f;  o1[1] = 1.0f;
                f32x2 nv = __builtin_elementwise_fma(m2, qv, o1);
                f32x2 hp = hprev[jt * 2 + pr];
                f32x2 hn = __builtin_elementwise_fma(zv, hp - nv, nv);
                hprev[jt * 2 + pr] = hn;
                _Float16 hh0 = (_Float16)hn[0], hh1 = (_Float16)hn[1];
                f32x2 hi32; hi32[0] = (float)hh0; hi32[1] = (float)hh1;
                f32x2 lo2 = hn - hi32;               // pk_sub
                h4[2 * pr]     = hh0; h4[2 * pr + 1] = hh1;
                l4[2 * pr]     = (_Float16)lo2[0];
                l4[2 * pr + 1] = (_Float16)lo2[1];
                hv[2 * pr]     = hn[0];
                hv[2 * pr + 1] = hn[1];
            }
            int wi = jt * 256 + wibase;
            *(half4*)(lds16 + ownhi + ((t & 7) << 9) + wi) = h4;
            *(half4*)(lds16 + ownlo + ((t & 1) << 9) + wi) = l4;
            if (w == LL - 1 && t == capT) {
                lastF[bi16 * 33 + jt * 16 + quad * 4 + 0] = hv[0];
                lastF[bi16 * 33 + jt * 16 + quad * 4 + 1] = hv[1];
                lastF[bi16 * 33 + jt * 16 + quad * 4 + 2] = hv[2];
                lastF[bi16 * 33 + jt * 16 + quad * 4 + 3] = hv[3];
            }
        }
    };

    for (int t = 0; t < TT; t += 2) {
        // fwd sync: input panels for t, t+1 published by wave w-1
        if (w > 0) {
            while (__hip_atomic_load(&flagS[w - 1], __ATOMIC_ACQUIRE,
                                     __HIP_MEMORY_SCOPE_WORKGROUP) < t + 1)
                __builtin_amdgcn_s_sleep(1);
        }
        // bwd sync: writing t+1 reuses slot of t-7 — consumer must be done
        if (w < LL - 1) {
            while (__hip_atomic_load(&rflagS[w], __ATOMIC_ACQUIRE,
                                     __HIP_MEMORY_SCOPE_WORKGROUP) < t - 7)
                __builtin_amdgcn_s_sleep(1);
        }

        // wave 0: issue global x loads for t+2, t+3 early
        float4 xa0, xa1;
        bool dl0 = false, dl1 = false;
        if (xlane) {
            if (t + 2 < TT) {
                xa0 = *(const float4*)(x + (size_t)(t + 2) * BB * IN_DIM +
                                       (size_t)bg * 192 + lane * 4);
                dl0 = true;
            }
            if (t + 3 < TT) {
                xa1 = *(const float4*)(x + (size_t)(t + 3) * BB * IN_DIM +
                                       (size_t)bg * 192 + lane * 4);
                dl1 = true;
            }
        }

        substep(t);
        substep(t + 1);

        if (dl0) stage_x(xa0, t + 2);   // 4 x-slots: no overlap with t, t+1
        if (dl1) stage_x(xa1, t + 3);

        if (lane == 0) {
            // release: waits for this wave's DS ops (panel writes AND input
            // reads) to drain before publishing
            if (w < LL - 1)
                __hip_atomic_store(&flagS[w], t + 1, __ATOMIC_RELEASE,
                                   __HIP_MEMORY_SCOPE_WORKGROUP);
            if (w > 0)
                __hip_atomic_store(&rflagS[w - 1], t + 1, __ATOMIC_RELEASE,
                                   __HIP_MEMORY_SCOPE_WORKGROUP);
        }
    }

    // ---- fused FC head: wave 0 computes logits + log_softmax ----
    __syncthreads();   // lastF complete (capT <= TT-1)
    if (w == 0) {
        const int b = lane & 15;     // batch col
        const int c = lane >> 4;     // class
        float lg = fcb[c];
#pragma unroll
        for (int j = 0; j < HH; j++)
            lg = fmaf(fcW[c * HH + j], lastF[b * 33 + j], lg);
        float m = fmaxf(lg, __shfl_xor(lg, 16));
        m = fmaxf(m, __shfl_xor(m, 32));
        float e = __expf(lg - m);
        float s = e + __shfl_xor(e, 16);
        s += __shfl_xor(s, 32);
        float lse = m + logf(s);
        out[(size_t)(bg * 16 + b) * CC + c] = lg - lse;
    }
}

extern "C" void kernel_launch(void* const* d_in, const int* in_sizes, int n_in,
                              void* d_out, int out_size, void* d_ws, size_t ws_size,
                              hipStream_t stream)
{
    const float* x    = (const float*)d_in[0];
    const float* Wih0 = (const float*)d_in[1];
    const float* Whh0 = (const float*)d_in[2];
    const float* bih0 = (const float*)d_in[3];
    const float* bhh0 = (const float*)d_in[4];
    const float* Wih  = (const float*)d_in[5];
    const float* Whh  = (const float*)d_in[6];
    const float* bih  = (const float*)d_in[7];
    const float* bhh  = (const float*)d_in[8];
    const float* fcW  = (const float*)d_in[9];
    const float* fcb  = (const float*)d_in[10];
    const int*   lens = (const int*)d_in[11];
    float* out = (float*)d_out;

    gru_fused_mfma<<<dim3(BB / 16), dim3(NTH), 0, stream>>>(
        x, Wih0, Whh0, bih0, bhh0, Wih, Whh, bih, bhh, lens, fcW, fcb, out);
}

// Round 9
// 830.333 us; speedup vs baseline: 1.6939x; 1.0924x over previous
//
#include <hip/hip_runtime.h>
#include <math.h>

#define TT 512
#define BB 4096
#define IN_DIM 12
#define HH 32
#define LL 10
#define CC 4
#define NTH (LL * 64)        // 640 threads = 10 waves, one per layer

typedef _Float16 half8 __attribute__((ext_vector_type(8)));
typedef _Float16 half4 __attribute__((ext_vector_type(4)));
typedef float f32x4 __attribute__((ext_vector_type(4)));
typedef float f32x2 __attribute__((ext_vector_type(2)));

#define LOG2E 1.44269504088896340736f

// f16-unit offsets in the LDS arena (total 53248 f16 = 104 KB static):
//  H_HI: per-layer h hi panels, 8 slots (mod-8 of t) — cross-wave handoff
//  H_LO: per-layer h lo panels, 2 slots — own-layer recurrence
//  X_HI: wave-0 x panels, 4 slots — wave-internal
#define H_HI 0
#define H_LO (LL * 8 * 512)             // 40960
#define X_HI (H_LO + LL * 2 * 512)      // 51200
#define LDS16_TOT (X_HI + 4 * 512)      // 53248

#define MFMA_(A, B, C) C = __builtin_amdgcn_mfma_f32_16x16x32_f16(A, B, C, 0, 0, 0)

// Fused 10-layer GRU, temporal pipeline, MFMA cells, self-timed flags.
//
// Session ledger:
//  R1: batched-rcp ~neutral -> trans are cheap; VALUBusy includes MFMA.
//  R2: 4-wave multi-cell FAILED (VGPR 370 >> 196 -> serialized). TLP is
//      load-bearing. 10 waves => {3,3,2,2}/SIMD => hard cap 170 VGPR/wave.
//  R4/R5: pk-epilogue + 8-slot H_HI = -51us; s_setprio = -110us HARM. BANNED.
//  R6: M-split FAILED: cross-wave handshake inside the recurrence. BANNED.
//  R7: x8 unroll FAILED: I-fetch pressure. Unroll BANNED.
//  R8: fc_head fused: neutral (kept; single kernel).
//  R9 (this round): drop r/z-gate hi/lo compensation MFMAs (8 of 24).
//      r/z are sigmoid-protected: dropped terms inject ~2^-14.7/step into
//      a contractive recurrence, far below the 2^-7 error floor set by the
//      f16 inter-layer handoff. n-gate (tanh, unit slope) keeps FULL
//      compensation. 24 -> 16 MFMAs (-33% matrix-pipe issue), -16 VGPR.
__global__ __launch_bounds__(NTH, 2)
void gru_fused_mfma(const float* __restrict__ x,      // [T][B][12]
                    const float* __restrict__ Wih0,   // [96][12]
                    const float* __restrict__ Whh0,   // [96][32]
                    const float* __restrict__ bih0,   // [96]
                    const float* __restrict__ bhh0,   // [96]
                    const float* __restrict__ Wih,    // [9][96][32]
                    const float* __restrict__ Whh,    // [9][96][32]
                    const float* __restrict__ bih,    // [9][96]
                    const float* __restrict__ bhh,    // [9][96]
                    const int*   __restrict__ lengths,
                    const float* __restrict__ fcW,    // [C][H]
                    const float* __restrict__ fcb,    // [C]
                    float*       __restrict__ out)    // [B][C]
{
    __shared__ __align__(16) _Float16 lds16[LDS16_TOT];
    __shared__ float lastF[16 * 33];   // capT h rows, stride 33 (bank-safe)
    __shared__ int flagS[LL];    // producer progress
    __shared__ int rflagS[LL];   // consumer progress (indexed by producer)

    const int tid  = threadIdx.x;
    const int w    = tid >> 6;      // layer
    const int lane = tid & 63;
    const int bi16 = lane & 15;     // batch col within group
    const int quad = lane >> 4;
    const int bg   = blockIdx.x;    // batch group (16 elems)

    // ---- zero the arena (h0 = 0, zero-padding) + init flags ----
    {
        float4 z4 = make_float4(0.f, 0.f, 0.f, 0.f);
        float4* p = (float4*)lds16;
        for (int i = tid; i < LDS16_TOT / 8; i += NTH) p[i] = z4;
    }
    if (lane == 0) { flagS[w] = -1; rflagS[w] = -1; }
    __syncthreads();

    // ---- per-wave weight pointers ----
    const float *Wi, *Wh, *bivec, *bhvec;
    int wistride;
    if (w == 0) { Wi = Wih0; Wh = Whh0; bivec = bih0; bhvec = bhh0; wistride = IN_DIM; }
    else {
        Wi = Wih + (size_t)(w - 1) * 96 * HH;
        Wh = Whh + (size_t)(w - 1) * 96 * HH;
        bivec = bih + (size_t)(w - 1) * 96;
        bhvec = bhh + (size_t)(w - 1) * 96;
        wistride = HH;
    }

    // ---- stationary A-fragments (pre-scaled) ----
    // f0..f7: r/z tiles, pairs (chunk0=Wi, chunk1=Wh); f8,f9: IN (Wi);
    // f10,f11: HN (Wh). Wlo kept ONLY for the HN (tanh-path) frags.
    const int frow[12] = {0, 0, 16, 16, 32, 32, 48, 48, 64, 80, 64, 80};
    const int fchk[12] = {0, 1, 0, 1, 0, 1, 0, 1, 0, 0, 1, 1};
    half8 Whi[12], WloHN[2];
#pragma unroll
    for (int f = 0; f < 12; f++) {
        const float sc = (f < 8) ? -LOG2E : 2.0f * LOG2E;
        int row = frow[f] + bi16;
        const float* src; int kin;
        if (fchk[f] == 0) { src = Wi + (size_t)row * wistride; kin = wistride; }
        else              { src = Wh + (size_t)row * HH;       kin = HH; }
#pragma unroll
        for (int kk = 0; kk < 8; kk++) {
            int k = quad * 8 + kk;
            float v = (k < kin) ? src[k] * sc : 0.0f;
            _Float16 h = (_Float16)v;
            Whi[f][kk] = h;
            if (f >= 10) WloHN[f - 10][kk] = (_Float16)(v - (float)h);
        }
    }

    // ---- biases in registers (pre-scaled, per C-tile f32x4) ----
    f32x4 biasreg[8];
#pragma unroll
    for (int ct = 0; ct < 8; ct++) {
        int g = ct >> 1, jt = ct & 1;
#pragma unroll
        for (int r = 0; r < 4; r++) {
            int j = jt * 16 + quad * 4 + r;
            float v;
            if      (g == 0) v = -(bivec[j]      + bhvec[j])      * LOG2E;
            else if (g == 1) v = -(bivec[32 + j] + bhvec[32 + j]) * LOG2E;
            else if (g == 2) v = bivec[64 + j] * (2.0f * LOG2E);
            else             v = bhvec[64 + j] * (2.0f * LOG2E);
            biasreg[ct][r] = v;
        }
    }

    int capT = -1;   // last-layer capture timestep per lane
    if (w == LL - 1) {
        int len = lengths[bg * 16 + bi16];
        capT = ((len < 1) ? 1 : len) - 1;
    }

    const int laneoff = lane * 8;
    const int inbase  = (w == 0) ? X_HI : (H_HI + (w - 1) * 4096);
    const int inmask  = (w == 0) ? 3 : 7;
    const int ownhi   = H_HI + w * 4096;
    const int ownlo   = H_LO + w * 1024;
    const int wibase  = (quad >> 1) * 128 + bi16 * 8 + (quad & 1) * 4;

    // x staging constants (wave 0, lanes 0-47)
    const int xbb = lane / 3, xkg = lane - xbb * 3;
    const int xq   = (xkg == 2) ? 1 : 0;
    const int xoff = (xkg == 1) ? 4 : 0;
    const int xidx = xq * 128 + xbb * 8 + xoff;
    const bool xlane = (w == 0) && (lane < 48);

    auto stage_x = [&](const float4& xl, int t) {
        half4 h4;
        h4[0] = (_Float16)xl.x; h4[1] = (_Float16)xl.y;
        h4[2] = (_Float16)xl.z; h4[3] = (_Float16)xl.w;
        *(half4*)(lds16 + X_HI + ((t & 3) << 9) + xidx) = h4;
    };

    // stage x[0], x[1]
    if (xlane) {
        float4 x0 = *(const float4*)(x + (size_t)bg * 192 + lane * 4);
        float4 x1 = *(const float4*)(x + (size_t)BB * IN_DIM + (size_t)bg * 192 + lane * 4);
        stage_x(x0, 0);
        stage_x(x1, 1);
    }

    f32x2 hprev[4];   // hprev[jt*2+pr] = rows (2pr, 2pr+1) of jt-half
#pragma unroll
    for (int i = 0; i < 4; i++) { hprev[i][0] = 0.0f; hprev[i][1] = 0.0f; }

    __syncthreads();   // flags + h0 + x0/x1 visible before self-timed phase

    auto substep = [&](int t) {
        // B-fragments: input (f16 hi only) + own h (hi+lo)
        half8 bxh = *(const half8*)(lds16 + inbase + ((t & inmask) << 9) + laneoff);
        half8 bhh = *(const half8*)(lds16 + ownhi + (((t + 7) & 7) << 9) + laneoff);
        half8 bhl = *(const half8*)(lds16 + ownlo + (((t + 1) & 1) << 9) + laneoff);

        f32x4 acc[8];

        // 16 MFMAs: r/z tiles 2 each (hi-only, sigmoid-protected);
        // IN 1 each; HN 3 each (full hi/lo compensation on the tanh path).
#pragma unroll
        for (int ct = 0; ct < 4; ct++) {
            acc[ct] = __builtin_amdgcn_mfma_f32_16x16x32_f16(
                          Whi[ct * 2 + 0], bxh, biasreg[ct], 0, 0, 0);
            MFMA_(Whi[ct * 2 + 1], bhh, acc[ct]);
        }
#pragma unroll
        for (int jt = 0; jt < 2; jt++) {
            acc[4 + jt] = __builtin_amdgcn_mfma_f32_16x16x32_f16(
                              Whi[8 + jt], bxh, biasreg[4 + jt], 0, 0, 0);
            acc[6 + jt] = __builtin_amdgcn_mfma_f32_16x16x32_f16(
                              Whi[10 + jt], bhh, biasreg[6 + jt], 0, 0, 0);
            MFMA_(Whi[10 + jt], bhl, acc[6 + jt]);
            MFMA_(WloHN[jt],    bhh, acc[6 + jt]);
        }

        // Epilogue, f32x2-packed over row pairs; batched rcp.
#pragma unroll
        for (int jt = 0; jt < 2; jt++) {
            half4 h4, l4;
            float hv[4];
#pragma unroll
            for (int pr = 0; pr < 2; pr++) {
                f32x2 R2, Z2, I2, H2;
                R2[0] = acc[0 + jt][2 * pr]; R2[1] = acc[0 + jt][2 * pr + 1];
                Z2[0] = acc[2 + jt][2 * pr]; Z2[1] = acc[2 + jt][2 * pr + 1];
                I2[0] = acc[4 + jt][2 * pr]; I2[1] = acc[4 + jt][2 * pr + 1];
                H2[0] = acc[6 + jt][2 * pr]; H2[1] = acc[6 + jt][2 * pr + 1];
                f32x2 av, bv;
                av[0] = __builtin_amdgcn_exp2f(R2[0]);
                av[1] = __builtin_amdgcn_exp2f(R2[1]);
                bv[0] = __builtin_amdgcn_exp2f(Z2[0]);
                bv[1] = __builtin_amdgcn_exp2f(Z2[1]);
                av = av + 1.0f;                       // pk_add
                bv = bv + 1.0f;
                f32x2 pv = av * bv;                   // pk_mul
                float q  = __builtin_amdgcn_rcpf(pv[0] * pv[1]);
                f32x2 qs; qs[0] = q * pv[1]; qs[1] = q * pv[0];   // 1/p0, 1/p1
                f32x2 rv = qs * bv;                   // = 1/a
                f32x2 zv = qs * av;                   // = 1/b
                f32x2 na = __builtin_elementwise_fma(rv, H2, I2);
                f32x2 ea;
                ea[0] = __builtin_amdgcn_exp2f(na[0]);
                ea[1] = __builtin_amdgcn_exp2f(na[1]);
                f32x2 dv = ea + 1.0f;
                float qn = __builtin_amdgcn_rcpf(dv[0] * dv[1]);
                f32x2 qv; qv[0] = qn * dv[1]; qv[1] = qn * dv[0]; // 1/d0, 1/d1
                f32x2 m2; m2[0] = -2.0f; m2[1] = -2.0f;
                f32x2 o1; o1[0] = 1.0f;  o1[1] = 1.0f;
                f32x2 nv = __builtin_elementwise_fma(m2, qv, o1);
                f32x2 hp = hprev[jt * 2 + pr];
                f32x2 hn = __builtin_elementwise_fma(zv, hp - nv, nv);
                hprev[jt * 2 + pr] = hn;
                _Float16 hh0 = (_Float16)hn[0], hh1 = (_Float16)hn[1];
                f32x2 hi32; hi32[0] = (float)hh0; hi32[1] = (float)hh1;
                f32x2 lo2 = hn - hi32;               // pk_sub
                h4[2 * pr]     = hh0; h4[2 * pr + 1] = hh1;
                l4[2 * pr]     = (_Float16)lo2[0];
                l4[2 * pr + 1] = (_Float16)lo2[1];
                hv[2 * pr]     = hn[0];
                hv[2 * pr + 1] = hn[1];
            }
            int wi = jt * 256 + wibase;
            *(half4*)(lds16 + ownhi + ((t & 7) << 9) + wi) = h4;
            *(half4*)(lds16 + ownlo + ((t & 1) << 9) + wi) = l4;
            if (w == LL - 1 && t == capT) {
                lastF[bi16 * 33 + jt * 16 + quad * 4 + 0] = hv[0];
                lastF[bi16 * 33 + jt * 16 + quad * 4 + 1] = hv[1];
                lastF[bi16 * 33 + jt * 16 + quad * 4 + 2] = hv[2];
                lastF[bi16 * 33 + jt * 16 + quad * 4 + 3] = hv[3];
            }
        }
    };

    for (int t = 0; t < TT; t += 2) {
        // fwd sync: input panels for t, t+1 published by wave w-1
        if (w > 0) {
            while (__hip_atomic_load(&flagS[w - 1], __ATOMIC_ACQUIRE,
                                     __HIP_MEMORY_SCOPE_WORKGROUP) < t + 1)
                __builtin_amdgcn_s_sleep(1);
        }
        // bwd sync: writing t+1 reuses slot of t-7 — consumer must be done
        if (w < LL - 1) {
            while (__hip_atomic_load(&rflagS[w], __ATOMIC_ACQUIRE,
                                     __HIP_MEMORY_SCOPE_WORKGROUP) < t - 7)
                __builtin_amdgcn_s_sleep(1);
        }

        // wave 0: issue global x loads for t+2, t+3 early
        float4 xa0, xa1;
        bool dl0 = false, dl1 = false;
        if (xlane) {
            if (t + 2 < TT) {
                xa0 = *(const float4*)(x + (size_t)(t + 2) * BB * IN_DIM +
                                       (size_t)bg * 192 + lane * 4);
                dl0 = true;
            }
            if (t + 3 < TT) {
                xa1 = *(const float4*)(x + (size_t)(t + 3) * BB * IN_DIM +
                                       (size_t)bg * 192 + lane * 4);
                dl1 = true;
            }
        }

        substep(t);
        substep(t + 1);

        if (dl0) stage_x(xa0, t + 2);   // 4 x-slots: no overlap with t, t+1
        if (dl1) stage_x(xa1, t + 3);

        if (lane == 0) {
            // release: waits for this wave's DS ops (panel writes AND input
            // reads) to drain before publishing
            if (w < LL - 1)
                __hip_atomic_store(&flagS[w], t + 1, __ATOMIC_RELEASE,
                                   __HIP_MEMORY_SCOPE_WORKGROUP);
            if (w > 0)
                __hip_atomic_store(&rflagS[w - 1], t + 1, __ATOMIC_RELEASE,
                                   __HIP_MEMORY_SCOPE_WORKGROUP);
        }
    }

    // ---- fused FC head: wave 0 computes logits + log_softmax ----
    __syncthreads();   // lastF complete (capT <= TT-1)
    if (w == 0) {
        const int b = lane & 15;     // batch col
        const int c = lane >> 4;     // class
        float lg = fcb[c];
#pragma unroll
        for (int j = 0; j < HH; j++)
            lg = fmaf(fcW[c * HH + j], lastF[b * 33 + j], lg);
        float m = fmaxf(lg, __shfl_xor(lg, 16));
        m = fmaxf(m, __shfl_xor(m, 32));
        float e = __expf(lg - m);
        float s = e + __shfl_xor(e, 16);
        s += __shfl_xor(s, 32);
        float lse = m + logf(s);
        out[(size_t)(bg * 16 + b) * CC + c] = lg - lse;
    }
}

extern "C" void kernel_launch(void* const* d_in, const int* in_sizes, int n_in,
                              void* d_out, int out_size, void* d_ws, size_t ws_size,
                              hipStream_t stream)
{
    const float* x    = (const float*)d_in[0];
    const float* Wih0 = (const float*)d_in[1];
    const float* Whh0 = (const float*)d_in[2];
    const float* bih0 = (const float*)d_in[3];
    const float* bhh0 = (const float*)d_in[4];
    const float* Wih  = (const float*)d_in[5];
    const float* Whh  = (const float*)d_in[6];
    const float* bih  = (const float*)d_in[7];
    const float* bhh  = (const float*)d_in[8];
    const float* fcW  = (const float*)d_in[9];
    const float* fcb  = (const float*)d_in[10];
    const int*   lens = (const int*)d_in[11];
    float* out = (float*)d_out;

    gru_fused_mfma<<<dim3(BB / 16), dim3(NTH), 0, stream>>>(
        x, Wih0, Whh0, bih0, bhh0, Wih, Whh, bih, bhh, lens, fcW, fcb, out);
}